// Round 2
// baseline (33878.571 us; speedup 1.0000x reference)
//
#include <hip/hip_runtime.h>
#include <math.h>
#include <limits.h>

#define B32 32
#define KD 1024
#define HID 1024
#define VOC 32000
#define NL 3
#define TN 128
#define BKC 32
#define ASTR 36
#define WSTR 68
#define GEMM_THREADS 128
#define KS_GRU 4

typedef __attribute__((ext_vector_type(8))) short bf16x8;
typedef __attribute__((ext_vector_type(16))) float f32x16;

__device__ __forceinline__ float sigmoidf_(float x) { return 1.0f / (1.0f + expf(-x)); }

__device__ __forceinline__ unsigned short f2bf(float f) {
    unsigned u = __float_as_uint(f);
    u = u + 0x7fffu + ((u >> 16) & 1u);
    return (unsigned short)(u >> 16);
}
__device__ __forceinline__ float bf2f(unsigned short h) {
    return __uint_as_float(((unsigned)h) << 16);
}
__device__ __forceinline__ f32x16 MF(bf16x8 a, bf16x8 b, f32x16 c) {
    return __builtin_amdgcn_mfma_f32_32x32x16_bf16(a, b, c, 0, 0, 0);
}

// ---------- conversion kernels ----------
__global__ __launch_bounds__(256)
void split_pair(const float* __restrict__ src, unsigned short* __restrict__ hi,
                unsigned short* __restrict__ lo, long n4)
{
    long i = (long)blockIdx.x * 256 + threadIdx.x;
    if (i >= n4) return;
    float4 f = ((const float4*)src)[i];
    ushort4 h, l;
    h.x = f2bf(f.x); l.x = f2bf(f.x - bf2f(h.x));
    h.y = f2bf(f.y); l.y = f2bf(f.y - bf2f(h.y));
    h.z = f2bf(f.z); l.z = f2bf(f.z - bf2f(h.z));
    h.w = f2bf(f.w); l.w = f2bf(f.w - bf2f(h.w));
    ((ushort4*)hi)[i] = h;
    ((ushort4*)lo)[i] = l;
}

__global__ __launch_bounds__(256)
void gather_split(const float* __restrict__ emb, const int* __restrict__ tokens,
                  unsigned short* __restrict__ xhi, unsigned short* __restrict__ xlo)
{
    int i = blockIdx.x * 256 + threadIdx.x;   // 8192 threads, one float4 each
    int b = i >> 8, q = i & 255;
    float4 f = ((const float4*)(emb + (size_t)tokens[b] * KD))[q];
    ushort4 h, l;
    h.x = f2bf(f.x); l.x = f2bf(f.x - bf2f(h.x));
    h.y = f2bf(f.y); l.y = f2bf(f.y - bf2f(h.y));
    h.z = f2bf(f.z); l.z = f2bf(f.z - bf2f(h.z));
    h.w = f2bf(f.w); l.w = f2bf(f.w - bf2f(h.w));
    ((ushort4*)(xhi + (size_t)b * KD))[q] = h;
    ((ushort4*)(xlo + (size_t)b * KD))[q] = l;
}

// ---------- fused GRU layer: MFMA bf16x2, gates + h-update in epilogue ----------
// 32 blocks x 384 threads (6 waves). Wave w = panel p: p<3 -> x @ w_ih gate p;
// p>=3 -> h @ w_hh gate p-3. Each block owns 32 j-columns.
__global__ __launch_bounds__(384)
void gru_mfma(const unsigned short* __restrict__ xhi, const unsigned short* __restrict__ xlo,
              const unsigned short* __restrict__ hinhi, const unsigned short* __restrict__ hinlo,
              unsigned short* __restrict__ houthi, unsigned short* __restrict__ houtlo,
              const unsigned short* __restrict__ wihhi, const unsigned short* __restrict__ wihlo,
              const unsigned short* __restrict__ whhhi, const unsigned short* __restrict__ whhlo,
              const float* __restrict__ bih, const float* __restrict__ bhh)
{
    __shared__ float Cex[6][B32][33];
    const int tid = threadIdx.x, w = tid >> 6, lane = tid & 63;
    const int col = lane & 31, kgrp = lane >> 5;
    const int j0 = blockIdx.x * 32;
    const int gate = (w < 3) ? w : w - 3;
    const unsigned short* Ahi = (w < 3) ? xhi : hinhi;
    const unsigned short* Alo = (w < 3) ? xlo : hinlo;
    const unsigned short* Whi = (w < 3) ? wihhi : whhhi;
    const unsigned short* Wlo = (w < 3) ? wihlo : whhlo;

    const unsigned short* arh = Ahi + (size_t)col * KD + kgrp * 8;
    const unsigned short* arl = Alo + (size_t)col * KD + kgrp * 8;
    const unsigned short* wrh = Whi + ((size_t)gate * KD + j0 + col) * KD + kgrp * 8;
    const unsigned short* wrl = Wlo + ((size_t)gate * KD + j0 + col) * KD + kgrp * 8;

    f32x16 acc = {0,0,0,0,0,0,0,0,0,0,0,0,0,0,0,0};
    bf16x8 ah0 = *(const bf16x8*)(arh),      al0 = *(const bf16x8*)(arl);
    bf16x8 wh0 = *(const bf16x8*)(wrh),      wl0 = *(const bf16x8*)(wrl);
    bf16x8 ah1 = *(const bf16x8*)(arh + 16), al1 = *(const bf16x8*)(arl + 16);
    bf16x8 wh1 = *(const bf16x8*)(wrh + 16), wl1 = *(const bf16x8*)(wrl + 16);

    for (int ks = 0; ks < 64; ++ks) {
        const int kn = ((ks + 2) & 63) * 16;
        bf16x8 ahn = *(const bf16x8*)(arh + kn), aln = *(const bf16x8*)(arl + kn);
        bf16x8 whn = *(const bf16x8*)(wrh + kn), wln = *(const bf16x8*)(wrl + kn);
        acc = MF(ah0, wh0, acc);
        acc = MF(al0, wh0, acc);
        acc = MF(ah0, wl0, acc);
        ah0 = ah1; al0 = al1; wh0 = wh1; wl0 = wl1;
        ah1 = ahn; al1 = aln; wh1 = whn; wl1 = wln;
    }

#pragma unroll
    for (int r = 0; r < 16; ++r) {
        int row = (r & 3) + 8 * (r >> 2) + 4 * kgrp;   // batch index
        Cex[w][row][col] = acc[r];
    }
    __syncthreads();

    for (int idx = tid; idx < B32 * 32; idx += 384) {
        int b = idx >> 5, j2 = idx & 31, j = j0 + j2;
        float rg = sigmoidf_(Cex[0][b][j2] + bih[j]          + Cex[3][b][j2] + bhh[j]);
        float zg = sigmoidf_(Cex[1][b][j2] + bih[KD + j]     + Cex[4][b][j2] + bhh[KD + j]);
        float ng = tanhf   (Cex[2][b][j2] + bih[2 * KD + j] + rg * (Cex[5][b][j2] + bhh[2 * KD + j]));
        float hold = bf2f(hinhi[(size_t)b * KD + j]) + bf2f(hinlo[(size_t)b * KD + j]);
        float hnew = (1.0f - zg) * ng + zg * hold;
        unsigned short hh = f2bf(hnew);
        houthi[(size_t)b * KD + j] = hh;
        houtlo[(size_t)b * KD + j] = f2bf(hnew - bf2f(hh));
    }
}

// ---------- logits: MFMA bf16x2, fused bias + out-store + argmax partials ----------
// 125 blocks x 512 threads (8 waves); wave covers 32 columns; block tile 256 cols.
__global__ __launch_bounds__(512)
void logits_mfma(const unsigned short* __restrict__ xhi, const unsigned short* __restrict__ xlo,
                 const unsigned short* __restrict__ whi, const unsigned short* __restrict__ wlo,
                 const float* __restrict__ bias, float* __restrict__ out, int t, int T,
                 float* __restrict__ pval, int* __restrict__ pidx)
{
    const int tid = threadIdx.x, w = tid >> 6, lane = tid & 63;
    const int col = lane & 31, kgrp = lane >> 5;
    const int n0 = blockIdx.x * 256 + w * 32;

    const unsigned short* arh = xhi + (size_t)col * KD + kgrp * 8;
    const unsigned short* arl = xlo + (size_t)col * KD + kgrp * 8;
    const unsigned short* wrh = whi + (size_t)(n0 + col) * KD + kgrp * 8;
    const unsigned short* wrl = wlo + (size_t)(n0 + col) * KD + kgrp * 8;

    f32x16 acc = {0,0,0,0,0,0,0,0,0,0,0,0,0,0,0,0};
    bf16x8 ah0 = *(const bf16x8*)(arh),      al0 = *(const bf16x8*)(arl);
    bf16x8 wh0 = *(const bf16x8*)(wrh),      wl0 = *(const bf16x8*)(wrl);
    bf16x8 ah1 = *(const bf16x8*)(arh + 16), al1 = *(const bf16x8*)(arl + 16);
    bf16x8 wh1 = *(const bf16x8*)(wrh + 16), wl1 = *(const bf16x8*)(wrl + 16);

    for (int ks = 0; ks < 64; ++ks) {
        const int kn = ((ks + 2) & 63) * 16;
        bf16x8 ahn = *(const bf16x8*)(arh + kn), aln = *(const bf16x8*)(arl + kn);
        bf16x8 whn = *(const bf16x8*)(wrh + kn), wln = *(const bf16x8*)(wrl + kn);
        acc = MF(ah0, wh0, acc);
        acc = MF(al0, wh0, acc);
        acc = MF(ah0, wl0, acc);
        ah0 = ah1; al0 = al1; wh0 = wh1; wl0 = wl1;
        ah1 = ahn; al1 = aln; wh1 = whn; wl1 = wln;
    }

    const float bb = bias[n0 + col];
    const int slot = blockIdx.x * 8 + w;   // both kgrp halves write disjoint b's of this slot

#pragma unroll
    for (int r = 0; r < 16; ++r) {
        int b = (r & 3) + 8 * (r >> 2) + 4 * kgrp;
        float v = acc[r] + bb;
        out[((size_t)b * T + t) * VOC + n0 + col] = v;
        float bv = v; int bi = n0 + col;
#pragma unroll
        for (int m = 1; m < 32; m <<= 1) {
            float ov = __shfl_xor(bv, m);
            int   oi = __shfl_xor(bi, m);
            if (ov > bv || (ov == bv && oi < bi)) { bv = ov; bi = oi; }
        }
        if (col == 0) {
            pval[(size_t)slot * B32 + b] = bv;
            pidx[(size_t)slot * B32 + b] = bi;
        }
    }
}

__global__ __launch_bounds__(256)
void amax_final(const float* __restrict__ pval, const int* __restrict__ pidx,
                int nblk, int* __restrict__ tokens)
{
    int tid = threadIdx.x;
    int b = tid >> 3, l8 = tid & 7;
    float bv = -INFINITY; int bi = INT_MAX;
    for (int q = l8; q < nblk; q += 8) {
        float v = pval[(size_t)q * B32 + b]; int ii = pidx[(size_t)q * B32 + b];
        if (v > bv || (v == bv && ii < bi)) { bv = v; bi = ii; }
    }
#pragma unroll
    for (int off = 1; off < 8; off <<= 1) {
        float ov = __shfl_xor(bv, off);
        int   oi = __shfl_xor(bi, off);
        if (ov > bv || (ov == bv && oi < bi)) { bv = ov; bi = oi; }
    }
    if (l8 == 0) tokens[b] = bi;
}

// ---------- fp32 fallback-path kernels (round-1, proven) ----------
__global__ __launch_bounds__(GEMM_THREADS)
void gemm_k1024(const float* __restrict__ Ax, const float* __restrict__ Ah,
                const float* __restrict__ emb, const int* __restrict__ tokens, int gather0,
                const float* __restrict__ Wx, const float* __restrict__ Wh,
                const float* __restrict__ bias,
                float* __restrict__ C, int N, int KS)
{
    __shared__ float As[BKC * ASTR];
    __shared__ float Ws[2 * BKC * WSTR];
    const int tid = threadIdx.x;
    const int sel = blockIdx.y;
    const int ks  = blockIdx.x % KS;
    const int nt  = blockIdx.x / KS;
    const int n0  = nt * TN;
    const int klen = KD / KS;
    const int k0 = ks * klen;
    const float* A = sel ? Ah : Ax;
    const float* W = sel ? Wh : Wx;
    const bool gather = (sel == 0) && (gather0 != 0);

    const int tb = tid & 7;
    const int tn = tid >> 3;
    const int s_kq = tid & 7;
    const int s_r  = tid >> 3;

    const float* arow0;
    const float* arow1;
    if (gather) {
        arow0 = emb + (size_t)tokens[s_r] * KD;
        arow1 = emb + (size_t)tokens[s_r + 16] * KD;
    } else {
        arow0 = A + (size_t)s_r * KD;
        arow1 = A + (size_t)(s_r + 16) * KD;
    }
    const float* wrow = W + (size_t)(n0 + s_r) * KD;

    float acc[4][8];
#pragma unroll
    for (int i = 0; i < 4; ++i)
#pragma unroll
        for (int j = 0; j < 8; ++j) acc[i][j] = 0.0f;

    for (int kc = 0; kc < klen; kc += BKC) {
        const int kb = k0 + kc + s_kq * 4;
        float4 a0 = *(const float4*)(arow0 + kb);
        float4 a1 = *(const float4*)(arow1 + kb);
        float4 wv[8];
#pragma unroll
        for (int hh = 0; hh < 8; ++hh)
            wv[hh] = *(const float4*)(wrow + (size_t)hh * 16 * KD + kb);

        __syncthreads();
#pragma unroll
        for (int j = 0; j < 4; ++j) {
            As[(s_kq * 4 + j) * ASTR + s_r]      = ((const float*)&a0)[j];
            As[(s_kq * 4 + j) * ASTR + s_r + 16] = ((const float*)&a1)[j];
        }
#pragma unroll
        for (int hh = 0; hh < 8; ++hh) {
            int row = s_r + hh * 16;
            int half = row >> 6;
            int c = row & 63;
            float* wbase = &Ws[half * BKC * WSTR];
#pragma unroll
            for (int j = 0; j < 4; ++j)
                wbase[(s_kq * 4 + j) * WSTR + c] = ((const float*)&wv[hh])[j];
        }
        __syncthreads();

#pragma unroll
        for (int kk = 0; kk < BKC; ++kk) {
            float4 av = *(const float4*)&As[kk * ASTR + 4 * tb];
            float4 w0 = *(const float4*)&Ws[kk * WSTR + 4 * tn];
            float4 w1 = *(const float4*)&Ws[BKC * WSTR + kk * WSTR + 4 * tn];
#pragma unroll
            for (int i = 0; i < 4; ++i) {
                float a = ((const float*)&av)[i];
                acc[i][0] += a * w0.x; acc[i][1] += a * w0.y;
                acc[i][2] += a * w0.z; acc[i][3] += a * w0.w;
                acc[i][4] += a * w1.x; acc[i][5] += a * w1.y;
                acc[i][6] += a * w1.z; acc[i][7] += a * w1.w;
            }
        }
    }

    const int slice = sel * KS + ks;
    float* Cb = C + (size_t)slice * B32 * N;
    float4 bA = make_float4(0.f, 0.f, 0.f, 0.f), bB = bA;
    if (bias != nullptr && ks == 0) {
        bA = *(const float4*)&bias[n0 + 4 * tn];
        bB = *(const float4*)&bias[n0 + 64 + 4 * tn];
    }
#pragma unroll
    for (int i = 0; i < 4; ++i) {
        int b = 4 * tb + i;
        float4 vA = make_float4(acc[i][0] + bA.x, acc[i][1] + bA.y, acc[i][2] + bA.z, acc[i][3] + bA.w);
        float4 vB = make_float4(acc[i][4] + bB.x, acc[i][5] + bB.y, acc[i][6] + bB.z, acc[i][7] + bB.w);
        *(float4*)&Cb[(size_t)b * N + n0 + 4 * tn]       = vA;
        *(float4*)&Cb[(size_t)b * N + n0 + 64 + 4 * tn]  = vB;
    }
}

__global__ __launch_bounds__(256)
void gru_gates(const float* __restrict__ G,
               const float* __restrict__ bih, const float* __restrict__ bhh,
               float* __restrict__ hl)
{
    int idx = blockIdx.x * 256 + threadIdx.x;
    int b = idx >> 10, j = idx & 1023;
    float xr = 0, xz = 0, xn = 0, hr = 0, hz = 0, hn = 0;
#pragma unroll
    for (int ks = 0; ks < KS_GRU; ++ks) {
        const float* gx = G + ((size_t)ks * B32 + b) * 3072;
        const float* gh = G + ((size_t)(KS_GRU + ks) * B32 + b) * 3072;
        xr += gx[j];        xz += gx[1024 + j];  xn += gx[2048 + j];
        hr += gh[j];        hz += gh[1024 + j];  hn += gh[2048 + j];
    }
    float r = sigmoidf_(xr + bih[j] + hr + bhh[j]);
    float z = sigmoidf_(xz + bih[1024 + j] + hz + bhh[1024 + j]);
    float n = tanhf(xn + bih[2048 + j] + r * (hn + bhh[2048 + j]));
    float ho = hl[idx];
    hl[idx] = (1.0f - z) * n + z * ho;
}

__global__ __launch_bounds__(GEMM_THREADS)
void logits_kernel(const float* __restrict__ x,
                   const float* __restrict__ W, const float* __restrict__ bias,
                   float* __restrict__ out, int t, int T,
                   float* __restrict__ pval, int* __restrict__ pidx)
{
    __shared__ float As[BKC * ASTR];
    __shared__ float Ws[2 * BKC * WSTR];
    __shared__ float rval[B32 * 16];
    __shared__ int   ridx[B32 * 16];
    const int tid = threadIdx.x;
    const int n0 = blockIdx.x * TN;
    const int tb = tid & 7;
    const int tn = tid >> 3;
    const int s_kq = tid & 7;
    const int s_r  = tid >> 3;

    const float* arow0 = x + (size_t)s_r * KD;
    const float* arow1 = x + (size_t)(s_r + 16) * KD;
    const float* wrow  = W + (size_t)(n0 + s_r) * KD;

    float acc[4][8];
#pragma unroll
    for (int i = 0; i < 4; ++i)
#pragma unroll
        for (int j = 0; j < 8; ++j) acc[i][j] = 0.0f;

    for (int kc = 0; kc < KD; kc += BKC) {
        const int kb = kc + s_kq * 4;
        float4 a0 = *(const float4*)(arow0 + kb);
        float4 a1 = *(const float4*)(arow1 + kb);
        float4 wv[8];
#pragma unroll
        for (int hh = 0; hh < 8; ++hh)
            wv[hh] = *(const float4*)(wrow + (size_t)hh * 16 * KD + kb);

        __syncthreads();
#pragma unroll
        for (int j = 0; j < 4; ++j) {
            As[(s_kq * 4 + j) * ASTR + s_r]      = ((const float*)&a0)[j];
            As[(s_kq * 4 + j) * ASTR + s_r + 16] = ((const float*)&a1)[j];
        }
#pragma unroll
        for (int hh = 0; hh < 8; ++hh) {
            int row = s_r + hh * 16;
            int half = row >> 6;
            int c = row & 63;
            float* wbase = &Ws[half * BKC * WSTR];
#pragma unroll
            for (int j = 0; j < 4; ++j)
                wbase[(s_kq * 4 + j) * WSTR + c] = ((const float*)&wv[hh])[j];
        }
        __syncthreads();

#pragma unroll
        for (int kk = 0; kk < BKC; ++kk) {
            float4 av = *(const float4*)&As[kk * ASTR + 4 * tb];
            float4 w0 = *(const float4*)&Ws[kk * WSTR + 4 * tn];
            float4 w1 = *(const float4*)&Ws[BKC * WSTR + kk * WSTR + 4 * tn];
#pragma unroll
            for (int i = 0; i < 4; ++i) {
                float a = ((const float*)&av)[i];
                acc[i][0] += a * w0.x; acc[i][1] += a * w0.y;
                acc[i][2] += a * w0.z; acc[i][3] += a * w0.w;
                acc[i][4] += a * w1.x; acc[i][5] += a * w1.y;
                acc[i][6] += a * w1.z; acc[i][7] += a * w1.w;
            }
        }
    }

    float4 bA = *(const float4*)&bias[n0 + 4 * tn];
    float4 bB = *(const float4*)&bias[n0 + 64 + 4 * tn];

    float bestv[4]; int besti[4];
#pragma unroll
    for (int i = 0; i < 4; ++i) { bestv[i] = -INFINITY; besti[i] = INT_MAX; }

#pragma unroll
    for (int i = 0; i < 4; ++i) {
        int b = 4 * tb + i;
        float* orow = out + ((size_t)b * T + t) * VOC;
        float4 vA = make_float4(acc[i][0] + bA.x, acc[i][1] + bA.y, acc[i][2] + bA.z, acc[i][3] + bA.w);
        float4 vB = make_float4(acc[i][4] + bB.x, acc[i][5] + bB.y, acc[i][6] + bB.z, acc[i][7] + bB.w);
        *(float4*)&orow[n0 + 4 * tn]      = vA;
        *(float4*)&orow[n0 + 64 + 4 * tn] = vB;
#pragma unroll
        for (int j = 0; j < 4; ++j) {
            float v = ((const float*)&vA)[j]; int c = n0 + 4 * tn + j;
            if (v > bestv[i] || (v == bestv[i] && c < besti[i])) { bestv[i] = v; besti[i] = c; }
        }
#pragma unroll
        for (int j = 0; j < 4; ++j) {
            float v = ((const float*)&vB)[j]; int c = n0 + 64 + 4 * tn + j;
            if (v > bestv[i] || (v == bestv[i] && c < besti[i])) { bestv[i] = v; besti[i] = c; }
        }
    }
#pragma unroll
    for (int i = 0; i < 4; ++i) {
        rval[(4 * tb + i) * 16 + tn] = bestv[i];
        ridx[(4 * tb + i) * 16 + tn] = besti[i];
    }
    __syncthreads();
    if (tid < B32) {
        int b = tid;
        float bv = -INFINITY; int bi = INT_MAX;
        for (int q = 0; q < 16; ++q) {
            float v = rval[b * 16 + q]; int ii = ridx[b * 16 + q];
            if (v > bv || (v == bv && ii < bi)) { bv = v; bi = ii; }
        }
        pval[(size_t)blockIdx.x * B32 + b] = bv;
        pidx[(size_t)blockIdx.x * B32 + b] = bi;
    }
}

// ---------- host ----------
extern "C" void kernel_launch(void* const* d_in, const int* in_sizes, int n_in,
                              void* d_out, int out_size, void* d_ws, size_t ws_size,
                              hipStream_t stream)
{
    const float* z    = (const float*)d_in[0];
    const float* emb  = (const float*)d_in[1];
    const float* wlat = (const float*)d_in[2];
    const float* blat = (const float*)d_in[3];
    const float* wih  = (const float*)d_in[4];
    const float* whh  = (const float*)d_in[5];
    const float* bih  = (const float*)d_in[6];
    const float* bhh  = (const float*)d_in[7];
    const float* fcw  = (const float*)d_in[8];
    const float* fcb  = (const float*)d_in[9];
    float* out = (float*)d_out;
    const int T = out_size / (B32 * VOC);   // 128

    const size_t NEED = 210000000;
    if (ws_size >= NEED) {
        // ---- fast path: bf16x2 MFMA ----
        char* p = (char*)d_ws;
        auto take = [&](size_t bytes) { char* r = p; p += (bytes + 255) & ~(size_t)255; return r; };
        unsigned short* fcw_hi = (unsigned short*)take((size_t)VOC * KD * 2);
        unsigned short* fcw_lo = (unsigned short*)take((size_t)VOC * KD * 2);
        unsigned short* wih_hi = (unsigned short*)take((size_t)NL * 3 * KD * KD * 2);
        unsigned short* wih_lo = (unsigned short*)take((size_t)NL * 3 * KD * KD * 2);
        unsigned short* whh_hi = (unsigned short*)take((size_t)NL * 3 * KD * KD * 2);
        unsigned short* whh_lo = (unsigned short*)take((size_t)NL * 3 * KD * KD * 2);
        unsigned short* hA_hi  = (unsigned short*)take((size_t)NL * B32 * KD * 2);
        unsigned short* hA_lo  = (unsigned short*)take((size_t)NL * B32 * KD * 2);
        unsigned short* hB_hi  = (unsigned short*)take((size_t)NL * B32 * KD * 2);
        unsigned short* hB_lo  = (unsigned short*)take((size_t)NL * B32 * KD * 2);
        unsigned short* x_hi   = (unsigned short*)take((size_t)B32 * KD * 2);
        unsigned short* x_lo   = (unsigned short*)take((size_t)B32 * KD * 2);
        float* h32    = (float*)take((size_t)B32 * NL * KD * 4);
        float* pval   = (float*)take(1000 * B32 * 4);
        int*   pidx   = (int*)take(1000 * B32 * 4);
        int*   tokens = (int*)take(B32 * 4);

        hipMemsetAsync(tokens, 0, B32 * sizeof(int), stream);

        long n4;
        n4 = (long)VOC * KD / 4;
        split_pair<<<(unsigned)((n4 + 255) / 256), 256, 0, stream>>>(fcw, fcw_hi, fcw_lo, n4);
        n4 = (long)NL * 3 * KD * KD / 4;
        split_pair<<<(unsigned)((n4 + 255) / 256), 256, 0, stream>>>(wih, wih_hi, wih_lo, n4);
        split_pair<<<(unsigned)((n4 + 255) / 256), 256, 0, stream>>>(whh, whh_hi, whh_lo, n4);

        // hidden init: z @ w_lat^T + b_lat (fp32), then split; flat layout == reshape(L,B,H)
        gemm_k1024<<<dim3(NL * KD / TN, 1), GEMM_THREADS, 0, stream>>>(
            z, nullptr, nullptr, nullptr, 0, wlat, nullptr, blat, h32, NL * KD, 1);
        n4 = (long)NL * B32 * KD / 4;
        split_pair<<<(unsigned)((n4 + 255) / 256), 256, 0, stream>>>(h32, hA_hi, hA_lo, n4);

        for (int t = 0; t < T; ++t) {
            unsigned short* cur_hi = (t & 1) ? hB_hi : hA_hi;
            unsigned short* cur_lo = (t & 1) ? hB_lo : hA_lo;
            unsigned short* nxt_hi = (t & 1) ? hA_hi : hB_hi;
            unsigned short* nxt_lo = (t & 1) ? hA_lo : hB_lo;

            gather_split<<<32, 256, 0, stream>>>(emb, tokens, x_hi, x_lo);

            for (int l = 0; l < NL; ++l) {
                const unsigned short* xin_hi = (l == 0) ? x_hi : nxt_hi + (size_t)(l - 1) * B32 * KD;
                const unsigned short* xin_lo = (l == 0) ? x_lo : nxt_lo + (size_t)(l - 1) * B32 * KD;
                gru_mfma<<<32, 384, 0, stream>>>(
                    xin_hi, xin_lo,
                    cur_hi + (size_t)l * B32 * KD, cur_lo + (size_t)l * B32 * KD,
                    nxt_hi + (size_t)l * B32 * KD, nxt_lo + (size_t)l * B32 * KD,
                    wih_hi + (size_t)l * 3 * KD * KD, wih_lo + (size_t)l * 3 * KD * KD,
                    whh_hi + (size_t)l * 3 * KD * KD, whh_lo + (size_t)l * 3 * KD * KD,
                    bih + (size_t)l * 3 * KD, bhh + (size_t)l * 3 * KD);
            }
            logits_mfma<<<VOC / 256, 512, 0, stream>>>(
                nxt_hi + (size_t)2 * B32 * KD, nxt_lo + (size_t)2 * B32 * KD,
                fcw_hi, fcw_lo, fcb, out, t, T, pval, pidx);
            amax_final<<<1, 256, 0, stream>>>(pval, pidx, 1000, tokens);
        }
    } else {
        // ---- fallback: round-1 fp32 path ----
        float* h      = (float*)d_ws;
        float* G      = h + (size_t)B32 * NL * HID;
        float* pval   = G + (size_t)2 * KS_GRU * B32 * NL * HID;
        int*   pidx   = (int*)(pval + (VOC / TN) * B32);
        int*   tokens = (int*)(pidx + (VOC / TN) * B32);

        hipMemsetAsync(tokens, 0, B32 * sizeof(int), stream);

        gemm_k1024<<<dim3(NL * HID / TN, 1), GEMM_THREADS, 0, stream>>>(
            z, nullptr, nullptr, nullptr, 0, wlat, nullptr, blat, h, NL * HID, 1);

        for (int t = 0; t < T; ++t) {
            for (int l = 0; l < NL; ++l) {
                const float* xA = (l == 0) ? nullptr : (h + (size_t)(l - 1) * B32 * HID);
                dim3 gg((NL * HID / TN) * KS_GRU, 2);
                gemm_k1024<<<gg, GEMM_THREADS, 0, stream>>>(
                    xA, h + (size_t)l * B32 * HID, emb, tokens, (l == 0) ? 1 : 0,
                    wih + (size_t)l * NL * HID * KD, whh + (size_t)l * NL * HID * KD,
                    nullptr, G, NL * HID, KS_GRU);
                gru_gates<<<B32 * HID / 256, 256, 0, stream>>>(
                    G, bih + (size_t)l * NL * HID, bhh + (size_t)l * NL * HID,
                    h + (size_t)l * B32 * HID);
            }
            logits_kernel<<<VOC / TN, GEMM_THREADS, 0, stream>>>(
                h + (size_t)2 * B32 * HID, fcw, fcb, out, t, T, pval, pidx);
            amax_final<<<1, 256, 0, stream>>>(pval, pidx, VOC / TN, tokens);
        }
    }
}

// Round 3
// 14976.486 us; speedup vs baseline: 2.2621x; 2.2621x over previous
//
#include <hip/hip_runtime.h>
#include <math.h>
#include <limits.h>

#define B32 32
#define KD 1024
#define HID 1024
#define VOC 32000
#define NL 3
#define TN 128
#define BKC 32
#define ASTR 36
#define WSTR 68
#define GEMM_THREADS 128
#define KS_GRU 4
#define NTILE_FC 1000   // VOC/32

typedef __attribute__((ext_vector_type(8))) short bf16x8;
typedef __attribute__((ext_vector_type(8))) unsigned short u16x8;
typedef __attribute__((ext_vector_type(16))) float f32x16;

__device__ __forceinline__ float sigmoidf_(float x) { return 1.0f / (1.0f + expf(-x)); }

__device__ __forceinline__ unsigned short f2bf(float f) {
    unsigned u = __float_as_uint(f);
    u = u + 0x7fffu + ((u >> 16) & 1u);
    return (unsigned short)(u >> 16);
}
__device__ __forceinline__ float bf2f(unsigned short h) {
    return __uint_as_float(((unsigned)h) << 16);
}
__device__ __forceinline__ f32x16 MF(bf16x8 a, bf16x8 b, f32x16 c) {
    return __builtin_amdgcn_mfma_f32_32x32x16_bf16(a, b, c, 0, 0, 0);
}

// ---------------- one-time pack: fp32 row-major [ntiles*32][1024] -> hi/lo fragment-packed
// packed idx within tile: (k>>3)*256 + row*8 + (k&7) ; tile stride 32768 shorts
__global__ __launch_bounds__(256)
void pack_w(const float* __restrict__ src, unsigned short* __restrict__ hi,
            unsigned short* __restrict__ lo, long ntiles)
{
    long tid = (long)blockIdx.x * 256 + threadIdx.x;
    long total = ntiles * 4096;           // chunks of 8 elems
    if (tid >= total) return;
    long tile = tid >> 12;
    int r = (int)(tid & 4095);
    int k8 = r >> 5, c = r & 31;
    const float* s = src + ((size_t)tile * 32 + c) * KD + k8 * 8;
    float4 f0 = ((const float4*)s)[0];
    float4 f1 = ((const float4*)s)[1];
    float ff[8] = {f0.x, f0.y, f0.z, f0.w, f1.x, f1.y, f1.z, f1.w};
    u16x8 h, l;
#pragma unroll
    for (int j = 0; j < 8; ++j) {
        unsigned short hh = f2bf(ff[j]);
        h[j] = hh;
        l[j] = f2bf(ff[j] - bf2f(hh));
    }
    size_t o = ((size_t)tile << 15) + (size_t)k8 * 256 + (size_t)c * 8;
    *(u16x8*)(hi + o) = h;
    *(u16x8*)(lo + o) = l;
}

// ---------------- per-step: argmax finalize (t>0) + embedding gather + fragment-pack x
__global__ __launch_bounds__(1024)
void token_pack(const float* __restrict__ emb,
                const float* __restrict__ pval, const int* __restrict__ pidx,
                int* __restrict__ tokens,
                unsigned short* __restrict__ xhi, unsigned short* __restrict__ xlo,
                int do_amax)
{
    const int tid = threadIdx.x;
    if (do_amax) {
        int b = tid >> 5, q0 = tid & 31;
        float bv = -INFINITY; int bi = INT_MAX;
        for (int q = q0; q < NTILE_FC; q += 32) {
            float v = pval[q * B32 + b]; int ii = pidx[q * B32 + b];
            if (v > bv || (v == bv && ii < bi)) { bv = v; bi = ii; }
        }
#pragma unroll
        for (int m = 1; m < 32; m <<= 1) {
            float ov = __shfl_xor(bv, m);
            int   oi = __shfl_xor(bi, m);
            if (ov > bv || (ov == bv && oi < bi)) { bv = ov; bi = oi; }
        }
        if (q0 == 0) tokens[b] = bi;
    }
    __syncthreads();
    for (int ch = tid; ch < 4096; ch += 1024) {
        int b = ch & 31, k8 = ch >> 5;
        const float* s = emb + (size_t)tokens[b] * KD + k8 * 8;
        float4 f0 = ((const float4*)s)[0];
        float4 f1 = ((const float4*)s)[1];
        float ff[8] = {f0.x, f0.y, f0.z, f0.w, f1.x, f1.y, f1.z, f1.w};
        u16x8 h, l;
#pragma unroll
        for (int j = 0; j < 8; ++j) {
            unsigned short hh = f2bf(ff[j]);
            h[j] = hh;
            l[j] = f2bf(ff[j] - bf2f(hh));
        }
        size_t o = (size_t)k8 * 256 + (size_t)b * 8;
        *(u16x8*)(xhi + o) = h;
        *(u16x8*)(xlo + o) = l;
    }
}

// ---------------- GRU GEMM: 128 blocks x 384 thr; block=(jt,ks4), wave=panel
// writes fp32 partials G[jt][ks4][panel][b][c]
__global__ __launch_bounds__(384)
void gru_gemm(const unsigned short* __restrict__ xhi, const unsigned short* __restrict__ xlo,
              const unsigned short* __restrict__ hhi, const unsigned short* __restrict__ hlo,
              const unsigned short* __restrict__ wihhi, const unsigned short* __restrict__ wihlo,
              const unsigned short* __restrict__ whhhi, const unsigned short* __restrict__ whhlo,
              float* __restrict__ G)
{
    const int bid = blockIdx.x;
    const int jt = bid >> 2, ks4 = bid & 3;
    const int w = threadIdx.x >> 6, lane = threadIdx.x & 63;
    const int gate = (w < 3) ? w : w - 3;
    const unsigned short* Ah = (w < 3) ? xhi : hhi;
    const unsigned short* Al = (w < 3) ? xlo : hlo;
    const size_t woff = ((size_t)(gate * 32 + jt)) << 15;
    const unsigned short* Wh = ((w < 3) ? wihhi : whhhi) + woff;
    const unsigned short* Wl = ((w < 3) ? wihlo : whhlo) + woff;

    const size_t lo8 = (size_t)lane * 8;
    const int kbase = ks4 * 16;

    f32x16 acc = {0,0,0,0,0,0,0,0,0,0,0,0,0,0,0,0};
    size_t o0 = (size_t)kbase * 512 + lo8;
    bf16x8 ah0 = *(const bf16x8*)(Ah + o0), al0 = *(const bf16x8*)(Al + o0);
    bf16x8 wh0 = *(const bf16x8*)(Wh + o0), wl0 = *(const bf16x8*)(Wl + o0);
#pragma unroll 4
    for (int i = 0; i < 16; ++i) {
        size_t on = (size_t)(kbase + ((i + 1) & 15)) * 512 + lo8;
        bf16x8 ahn = *(const bf16x8*)(Ah + on), aln = *(const bf16x8*)(Al + on);
        bf16x8 whn = *(const bf16x8*)(Wh + on), wln = *(const bf16x8*)(Wl + on);
        acc = MF(ah0, wh0, acc);
        acc = MF(al0, wh0, acc);
        acc = MF(ah0, wl0, acc);
        ah0 = ahn; al0 = aln; wh0 = whn; wl0 = wln;
    }

    const int kg = lane >> 5, c = lane & 31;
    float* Gb = G + (((size_t)(jt * 4 + ks4) * 6 + w) * B32) * 32;
#pragma unroll
    for (int r = 0; r < 16; ++r) {
        int b = (r & 3) + 8 * (r >> 2) + 4 * kg;
        Gb[b * 32 + c] = acc[r];
    }
}

// ---------------- gates: sum partials, activations, in-place packed h update
__global__ __launch_bounds__(256)
void gru_gates2(const float* __restrict__ G,
                const float* __restrict__ bih, const float* __restrict__ bhh,
                unsigned short* __restrict__ hhi, unsigned short* __restrict__ hlo)
{
    int idx = blockIdx.x * 256 + threadIdx.x;   // 32768
    int b = idx >> 10, j = idx & 1023;
    int jt = j >> 5, c = j & 31;
    float s0 = 0, s1 = 0, s2 = 0, s3 = 0, s4 = 0, s5 = 0;
#pragma unroll
    for (int ks = 0; ks < 4; ++ks) {
        const float* base = G + (((size_t)(jt * 4 + ks) * 6) * B32 + b) * 32 + c;
        s0 += base[0];
        s1 += base[1024];
        s2 += base[2048];
        s3 += base[3072];
        s4 += base[4096];
        s5 += base[5120];
    }
    float rg = sigmoidf_(s0 + bih[j] + s3 + bhh[j]);
    float zg = sigmoidf_(s1 + bih[KD + j] + s4 + bhh[KD + j]);
    float ng = tanhf(s2 + bih[2 * KD + j] + rg * (s5 + bhh[2 * KD + j]));
    size_t hp = (size_t)(j >> 3) * 256 + (size_t)b * 8 + (j & 7);
    float hold = bf2f(hhi[hp]) + bf2f(hlo[hp]);
    float hnew = (1.0f - zg) * ng + zg * hold;
    unsigned short hh = f2bf(hnew);
    hhi[hp] = hh;
    hlo[hp] = f2bf(hnew - bf2f(hh));
}

// ---------------- logits: 250 blocks x 256 thr (4 waves); wave = one 32-col tile
__global__ __launch_bounds__(256)
void logits2(const unsigned short* __restrict__ xhi, const unsigned short* __restrict__ xlo,
             const unsigned short* __restrict__ whi, const unsigned short* __restrict__ wlo,
             const float* __restrict__ bias, float* __restrict__ out, int t, int T,
             float* __restrict__ pval, int* __restrict__ pidx)
{
    const int w = threadIdx.x >> 6, lane = threadIdx.x & 63;
    const int tile = blockIdx.x * 4 + w;
    const int n0 = tile * 32;
    const unsigned short* Wh = whi + ((size_t)tile << 15);
    const unsigned short* Wl = wlo + ((size_t)tile << 15);
    const size_t lo8 = (size_t)lane * 8;

    f32x16 acc = {0,0,0,0,0,0,0,0,0,0,0,0,0,0,0,0};
    bf16x8 ah0 = *(const bf16x8*)(xhi + lo8),       al0 = *(const bf16x8*)(xlo + lo8);
    bf16x8 wh0 = *(const bf16x8*)(Wh + lo8),        wl0 = *(const bf16x8*)(Wl + lo8);
    bf16x8 ah1 = *(const bf16x8*)(xhi + 512 + lo8), al1 = *(const bf16x8*)(xlo + 512 + lo8);
    bf16x8 wh1 = *(const bf16x8*)(Wh + 512 + lo8),  wl1 = *(const bf16x8*)(Wl + 512 + lo8);

    for (int i = 0; i < 64; ++i) {
        size_t on = (size_t)((i + 2) & 63) * 512 + lo8;
        bf16x8 ahn = *(const bf16x8*)(xhi + on), aln = *(const bf16x8*)(xlo + on);
        bf16x8 whn = *(const bf16x8*)(Wh + on),  wln = *(const bf16x8*)(Wl + on);
        acc = MF(ah0, wh0, acc);
        acc = MF(al0, wh0, acc);
        acc = MF(ah0, wl0, acc);
        ah0 = ah1; al0 = al1; wh0 = wh1; wl0 = wl1;
        ah1 = ahn; al1 = aln; wh1 = whn; wl1 = wln;
    }

    const int kg = lane >> 5, col = lane & 31;
    const float bb = bias[n0 + col];
#pragma unroll
    for (int r = 0; r < 16; ++r) {
        int b = (r & 3) + 8 * (r >> 2) + 4 * kg;
        float v = acc[r] + bb;
        out[((size_t)b * T + t) * VOC + n0 + col] = v;
        float bv = v; int bi = n0 + col;
#pragma unroll
        for (int m = 1; m < 32; m <<= 1) {
            float ov = __shfl_xor(bv, m);
            int   oi = __shfl_xor(bi, m);
            if (ov > bv || (ov == bv && oi < bi)) { bv = ov; bi = oi; }
        }
        if (col == 0) {
            pval[tile * B32 + b] = bv;
            pidx[tile * B32 + b] = bi;
        }
    }
}

// ================= fp32 fallback (round-1, proven) =================
__global__ __launch_bounds__(GEMM_THREADS)
void gemm_k1024(const float* __restrict__ Ax, const float* __restrict__ Ah,
                const float* __restrict__ emb, const int* __restrict__ tokens, int gather0,
                const float* __restrict__ Wx, const float* __restrict__ Wh,
                const float* __restrict__ bias,
                float* __restrict__ C, int N, int KS)
{
    __shared__ float As[BKC * ASTR];
    __shared__ float Ws[2 * BKC * WSTR];
    const int tid = threadIdx.x;
    const int sel = blockIdx.y;
    const int ks  = blockIdx.x % KS;
    const int nt  = blockIdx.x / KS;
    const int n0  = nt * TN;
    const int klen = KD / KS;
    const int k0 = ks * klen;
    const float* A = sel ? Ah : Ax;
    const float* W = sel ? Wh : Wx;
    const bool gather = (sel == 0) && (gather0 != 0);

    const int tb = tid & 7;
    const int tn = tid >> 3;
    const int s_kq = tid & 7;
    const int s_r  = tid >> 3;

    const float* arow0;
    const float* arow1;
    if (gather) {
        arow0 = emb + (size_t)tokens[s_r] * KD;
        arow1 = emb + (size_t)tokens[s_r + 16] * KD;
    } else {
        arow0 = A + (size_t)s_r * KD;
        arow1 = A + (size_t)(s_r + 16) * KD;
    }
    const float* wrow = W + (size_t)(n0 + s_r) * KD;

    float acc[4][8];
#pragma unroll
    for (int i = 0; i < 4; ++i)
#pragma unroll
        for (int j = 0; j < 8; ++j) acc[i][j] = 0.0f;

    for (int kc = 0; kc < klen; kc += BKC) {
        const int kb = k0 + kc + s_kq * 4;
        float4 a0 = *(const float4*)(arow0 + kb);
        float4 a1 = *(const float4*)(arow1 + kb);
        float4 wv[8];
#pragma unroll
        for (int hh = 0; hh < 8; ++hh)
            wv[hh] = *(const float4*)(wrow + (size_t)hh * 16 * KD + kb);

        __syncthreads();
#pragma unroll
        for (int j = 0; j < 4; ++j) {
            As[(s_kq * 4 + j) * ASTR + s_r]      = ((const float*)&a0)[j];
            As[(s_kq * 4 + j) * ASTR + s_r + 16] = ((const float*)&a1)[j];
        }
#pragma unroll
        for (int hh = 0; hh < 8; ++hh) {
            int row = s_r + hh * 16;
            int half = row >> 6;
            int c = row & 63;
            float* wbase = &Ws[half * BKC * WSTR];
#pragma unroll
            for (int j = 0; j < 4; ++j)
                wbase[(s_kq * 4 + j) * WSTR + c] = ((const float*)&wv[hh])[j];
        }
        __syncthreads();

#pragma unroll
        for (int kk = 0; kk < BKC; ++kk) {
            float4 av = *(const float4*)&As[kk * ASTR + 4 * tb];
            float4 w0 = *(const float4*)&Ws[kk * WSTR + 4 * tn];
            float4 w1 = *(const float4*)&Ws[BKC * WSTR + kk * WSTR + 4 * tn];
#pragma unroll
            for (int i = 0; i < 4; ++i) {
                float a = ((const float*)&av)[i];
                acc[i][0] += a * w0.x; acc[i][1] += a * w0.y;
                acc[i][2] += a * w0.z; acc[i][3] += a * w0.w;
                acc[i][4] += a * w1.x; acc[i][5] += a * w1.y;
                acc[i][6] += a * w1.z; acc[i][7] += a * w1.w;
            }
        }
    }

    const int slice = sel * KS + ks;
    float* Cb = C + (size_t)slice * B32 * N;
    float4 bA = make_float4(0.f, 0.f, 0.f, 0.f), bB = bA;
    if (bias != nullptr && ks == 0) {
        bA = *(const float4*)&bias[n0 + 4 * tn];
        bB = *(const float4*)&bias[n0 + 64 + 4 * tn];
    }
#pragma unroll
    for (int i = 0; i < 4; ++i) {
        int b = 4 * tb + i;
        float4 vA = make_float4(acc[i][0] + bA.x, acc[i][1] + bA.y, acc[i][2] + bA.z, acc[i][3] + bA.w);
        float4 vB = make_float4(acc[i][4] + bB.x, acc[i][5] + bB.y, acc[i][6] + bB.z, acc[i][7] + bB.w);
        *(float4*)&Cb[(size_t)b * N + n0 + 4 * tn]       = vA;
        *(float4*)&Cb[(size_t)b * N + n0 + 64 + 4 * tn]  = vB;
    }
}

__global__ __launch_bounds__(256)
void gru_gates(const float* __restrict__ G,
               const float* __restrict__ bih, const float* __restrict__ bhh,
               float* __restrict__ hl)
{
    int idx = blockIdx.x * 256 + threadIdx.x;
    int b = idx >> 10, j = idx & 1023;
    float xr = 0, xz = 0, xn = 0, hr = 0, hz = 0, hn = 0;
#pragma unroll
    for (int ks = 0; ks < KS_GRU; ++ks) {
        const float* gx = G + ((size_t)ks * B32 + b) * 3072;
        const float* gh = G + ((size_t)(KS_GRU + ks) * B32 + b) * 3072;
        xr += gx[j];        xz += gx[1024 + j];  xn += gx[2048 + j];
        hr += gh[j];        hz += gh[1024 + j];  hn += gh[2048 + j];
    }
    float r = sigmoidf_(xr + bih[j] + hr + bhh[j]);
    float z = sigmoidf_(xz + bih[1024 + j] + hz + bhh[1024 + j]);
    float n = tanhf(xn + bih[2048 + j] + r * (hn + bhh[2048 + j]));
    float ho = hl[idx];
    hl[idx] = (1.0f - z) * n + z * ho;
}

__global__ __launch_bounds__(GEMM_THREADS)
void logits_kernel(const float* __restrict__ x,
                   const float* __restrict__ W, const float* __restrict__ bias,
                   float* __restrict__ out, int t, int T,
                   float* __restrict__ pval, int* __restrict__ pidx)
{
    __shared__ float As[BKC * ASTR];
    __shared__ float Ws[2 * BKC * WSTR];
    __shared__ float rval[B32 * 16];
    __shared__ int   ridx[B32 * 16];
    const int tid = threadIdx.x;
    const int n0 = blockIdx.x * TN;
    const int tb = tid & 7;
    const int tn = tid >> 3;
    const int s_kq = tid & 7;
    const int s_r  = tid >> 3;

    const float* arow0 = x + (size_t)s_r * KD;
    const float* arow1 = x + (size_t)(s_r + 16) * KD;
    const float* wrow  = W + (size_t)(n0 + s_r) * KD;

    float acc[4][8];
#pragma unroll
    for (int i = 0; i < 4; ++i)
#pragma unroll
        for (int j = 0; j < 8; ++j) acc[i][j] = 0.0f;

    for (int kc = 0; kc < KD; kc += BKC) {
        const int kb = kc + s_kq * 4;
        float4 a0 = *(const float4*)(arow0 + kb);
        float4 a1 = *(const float4*)(arow1 + kb);
        float4 wv[8];
#pragma unroll
        for (int hh = 0; hh < 8; ++hh)
            wv[hh] = *(const float4*)(wrow + (size_t)hh * 16 * KD + kb);

        __syncthreads();
#pragma unroll
        for (int j = 0; j < 4; ++j) {
            As[(s_kq * 4 + j) * ASTR + s_r]      = ((const float*)&a0)[j];
            As[(s_kq * 4 + j) * ASTR + s_r + 16] = ((const float*)&a1)[j];
        }
#pragma unroll
        for (int hh = 0; hh < 8; ++hh) {
            int row = s_r + hh * 16;
            int half = row >> 6;
            int c = row & 63;
            float* wbase = &Ws[half * BKC * WSTR];
#pragma unroll
            for (int j = 0; j < 4; ++j)
                wbase[(s_kq * 4 + j) * WSTR + c] = ((const float*)&wv[hh])[j];
        }
        __syncthreads();

#pragma unroll
        for (int kk = 0; kk < BKC; ++kk) {
            float4 av = *(const float4*)&As[kk * ASTR + 4 * tb];
            float4 w0 = *(const float4*)&Ws[kk * WSTR + 4 * tn];
            float4 w1 = *(const float4*)&Ws[BKC * WSTR + kk * WSTR + 4 * tn];
#pragma unroll
            for (int i = 0; i < 4; ++i) {
                float a = ((const float*)&av)[i];
                acc[i][0] += a * w0.x; acc[i][1] += a * w0.y;
                acc[i][2] += a * w0.z; acc[i][3] += a * w0.w;
                acc[i][4] += a * w1.x; acc[i][5] += a * w1.y;
                acc[i][6] += a * w1.z; acc[i][7] += a * w1.w;
            }
        }
    }

    float4 bA = *(const float4*)&bias[n0 + 4 * tn];
    float4 bB = *(const float4*)&bias[n0 + 64 + 4 * tn];

    float bestv[4]; int besti[4];
#pragma unroll
    for (int i = 0; i < 4; ++i) { bestv[i] = -INFINITY; besti[i] = INT_MAX; }

#pragma unroll
    for (int i = 0; i < 4; ++i) {
        int b = 4 * tb + i;
        float* orow = out + ((size_t)b * T + t) * VOC;
        float4 vA = make_float4(acc[i][0] + bA.x, acc[i][1] + bA.y, acc[i][2] + bA.z, acc[i][3] + bA.w);
        float4 vB = make_float4(acc[i][4] + bB.x, acc[i][5] + bB.y, acc[i][6] + bB.z, acc[i][7] + bB.w);
        *(float4*)&orow[n0 + 4 * tn]      = vA;
        *(float4*)&orow[n0 + 64 + 4 * tn] = vB;
#pragma unroll
        for (int j = 0; j < 4; ++j) {
            float v = ((const float*)&vA)[j]; int c = n0 + 4 * tn + j;
            if (v > bestv[i] || (v == bestv[i] && c < besti[i])) { bestv[i] = v; besti[i] = c; }
        }
#pragma unroll
        for (int j = 0; j < 4; ++j) {
            float v = ((const float*)&vB)[j]; int c = n0 + 64 + 4 * tn + j;
            if (v > bestv[i] || (v == bestv[i] && c < besti[i])) { bestv[i] = v; besti[i] = c; }
        }
    }
#pragma unroll
    for (int i = 0; i < 4; ++i) {
        rval[(4 * tb + i) * 16 + tn] = bestv[i];
        ridx[(4 * tb + i) * 16 + tn] = besti[i];
    }
    __syncthreads();
    if (tid < B32) {
        int b = tid;
        float bv = -INFINITY; int bi = INT_MAX;
        for (int q = 0; q < 16; ++q) {
            float v = rval[b * 16 + q]; int ii = ridx[b * 16 + q];
            if (v > bv || (v == bv && ii < bi)) { bv = v; bi = ii; }
        }
        pval[(size_t)blockIdx.x * B32 + b] = bv;
        pidx[(size_t)blockIdx.x * B32 + b] = bi;
    }
}

__global__ __launch_bounds__(256)
void amax_final(const float* __restrict__ pval, const int* __restrict__ pidx,
                int nblk, int* __restrict__ tokens)
{
    int tid = threadIdx.x;
    int b = tid >> 3, l8 = tid & 7;
    float bv = -INFINITY; int bi = INT_MAX;
    for (int q = l8; q < nblk; q += 8) {
        float v = pval[(size_t)q * B32 + b]; int ii = pidx[(size_t)q * B32 + b];
        if (v > bv || (v == bv && ii < bi)) { bv = v; bi = ii; }
    }
#pragma unroll
    for (int off = 1; off < 8; off <<= 1) {
        float ov = __shfl_xor(bv, off);
        int   oi = __shfl_xor(bi, off);
        if (ov > bv || (ov == bv && oi < bi)) { bv = ov; bi = oi; }
    }
    if (l8 == 0) tokens[b] = bi;
}

// ---------------- host ----------------
extern "C" void kernel_launch(void* const* d_in, const int* in_sizes, int n_in,
                              void* d_out, int out_size, void* d_ws, size_t ws_size,
                              hipStream_t stream)
{
    const float* z    = (const float*)d_in[0];
    const float* emb  = (const float*)d_in[1];
    const float* wlat = (const float*)d_in[2];
    const float* blat = (const float*)d_in[3];
    const float* wih  = (const float*)d_in[4];
    const float* whh  = (const float*)d_in[5];
    const float* bih  = (const float*)d_in[6];
    const float* bhh  = (const float*)d_in[7];
    const float* fcw  = (const float*)d_in[8];
    const float* fcb  = (const float*)d_in[9];
    float* out = (float*)d_out;
    const int T = out_size / (B32 * VOC);   // 128

    const size_t NEED = 211500000;
    if (ws_size >= NEED) {
        char* p = (char*)d_ws;
        auto take = [&](size_t bytes) { char* r = p; p += (bytes + 255) & ~(size_t)255; return r; };
        unsigned short* fcwPh = (unsigned short*)take((size_t)VOC * KD * 2);
        unsigned short* fcwPl = (unsigned short*)take((size_t)VOC * KD * 2);
        unsigned short* wihPh = (unsigned short*)take((size_t)NL * 3 * KD * KD * 2);
        unsigned short* wihPl = (unsigned short*)take((size_t)NL * 3 * KD * KD * 2);
        unsigned short* whhPh = (unsigned short*)take((size_t)NL * 3 * KD * KD * 2);
        unsigned short* whhPl = (unsigned short*)take((size_t)NL * 3 * KD * KD * 2);
        unsigned short* hPh   = (unsigned short*)take((size_t)NL * B32 * KD * 2);
        unsigned short* hPl   = (unsigned short*)take((size_t)NL * B32 * KD * 2);
        unsigned short* xPh   = (unsigned short*)take((size_t)B32 * KD * 2);
        unsigned short* xPl   = (unsigned short*)take((size_t)B32 * KD * 2);
        float* G      = (float*)take((size_t)32 * 4 * 6 * B32 * 32 * 4);
        float* h32    = (float*)take((size_t)B32 * NL * KD * 4);
        float* pval   = (float*)take((size_t)NTILE_FC * B32 * 4);
        int*   pidx   = (int*)take((size_t)NTILE_FC * B32 * 4);
        int*   tokens = (int*)take(B32 * 4);

        hipMemsetAsync(tokens, 0, B32 * sizeof(int), stream);

        // one-time weight packing (split hi/lo + MFMA fragment order)
        {
            long nt_fc = VOC / 32;                    // 1000
            long nt_g  = (long)NL * 3 * KD / 32;      // 288
            pack_w<<<(unsigned)((nt_fc * 4096 + 255) / 256), 256, 0, stream>>>(fcw, fcwPh, fcwPl, nt_fc);
            pack_w<<<(unsigned)((nt_g * 4096 + 255) / 256), 256, 0, stream>>>(wih, wihPh, wihPl, nt_g);
            pack_w<<<(unsigned)((nt_g * 4096 + 255) / 256), 256, 0, stream>>>(whh, whhPh, whhPl, nt_g);
        }

        // hidden init (fp32), then pack the 3 [32x1024] planes
        gemm_k1024<<<dim3(NL * KD / TN, 1), GEMM_THREADS, 0, stream>>>(
            z, nullptr, nullptr, nullptr, 0, wlat, nullptr, blat, h32, NL * KD, 1);
        pack_w<<<(unsigned)((3L * 4096 + 255) / 256), 256, 0, stream>>>(h32, hPh, hPl, 3);

        for (int t = 0; t < T; ++t) {
            token_pack<<<1, 1024, 0, stream>>>(emb, pval, pidx, tokens, xPh, xPl, t > 0 ? 1 : 0);

            for (int l = 0; l < NL; ++l) {
                const unsigned short* xh = (l == 0) ? xPh : hPh + (size_t)(l - 1) * B32 * KD;
                const unsigned short* xl = (l == 0) ? xPl : hPl + (size_t)(l - 1) * B32 * KD;
                gru_gemm<<<128, 384, 0, stream>>>(
                    xh, xl,
                    hPh + (size_t)l * B32 * KD, hPl + (size_t)l * B32 * KD,
                    wihPh + (size_t)l * 3 * KD * KD, wihPl + (size_t)l * 3 * KD * KD,
                    whhPh + (size_t)l * 3 * KD * KD, whhPl + (size_t)l * 3 * KD * KD,
                    G);
                gru_gates2<<<128, 256, 0, stream>>>(
                    G, bih + (size_t)l * 3 * KD, bhh + (size_t)l * 3 * KD,
                    hPh + (size_t)l * B32 * KD, hPl + (size_t)l * B32 * KD);
            }
            logits2<<<250, 256, 0, stream>>>(
                hPh + (size_t)2 * B32 * KD, hPl + (size_t)2 * B32 * KD,
                fcwPh, fcwPl, fcb, out, t, T, pval, pidx);
        }
    } else {
        // fallback: round-1 fp32 path
        float* h      = (float*)d_ws;
        float* G      = h + (size_t)B32 * NL * HID;
        float* pval   = G + (size_t)2 * KS_GRU * B32 * NL * HID;
        int*   pidx   = (int*)(pval + (VOC / TN) * B32);
        int*   tokens = (int*)(pidx + (VOC / TN) * B32);

        hipMemsetAsync(tokens, 0, B32 * sizeof(int), stream);

        gemm_k1024<<<dim3(NL * HID / TN, 1), GEMM_THREADS, 0, stream>>>(
            z, nullptr, nullptr, nullptr, 0, wlat, nullptr, blat, h, NL * HID, 1);

        for (int t = 0; t < T; ++t) {
            for (int l = 0; l < NL; ++l) {
                const float* xA = (l == 0) ? nullptr : (h + (size_t)(l - 1) * B32 * HID);
                dim3 gg((NL * HID / TN) * KS_GRU, 2);
                gemm_k1024<<<gg, GEMM_THREADS, 0, stream>>>(
                    xA, h + (size_t)l * B32 * HID, emb, tokens, (l == 0) ? 1 : 0,
                    wih + (size_t)l * NL * HID * KD, whh + (size_t)l * NL * HID * KD,
                    nullptr, G, NL * HID, KS_GRU);
                gru_gates<<<B32 * HID / 256, 256, 0, stream>>>(
                    G, bih + (size_t)l * NL * HID, bhh + (size_t)l * NL * HID,
                    h + (size_t)l * B32 * HID);
            }
            logits_kernel<<<VOC / TN, GEMM_THREADS, 0, stream>>>(
                h + (size_t)2 * B32 * HID, fcw, fcb, out, t, T, pval, pidx);
            amax_final<<<1, 256, 0, stream>>>(pval, pidx, VOC / TN, tokens);
        }
    }
}